// Round 3
// baseline (22337.479 us; speedup 1.0000x reference)
//
#include <hip/hip_runtime.h>
#include <math.h>

#define SEQ   512
#define BATCH 64
#define HID   512
#define NROW  1536                     // 3 gates * HID rows
#define XROW_FLOATS ((size_t)SEQ * NROW * BATCH)   // 201.3 MB
#define HBUF_FLOATS (2 * BATCH * HID)              // double-buffered h, [parity][b][j]
#define SBH ((size_t)SEQ * BATCH * HID)

__device__ __forceinline__ float sigf(float x) {
    return 1.f / (1.f + __expf(-x));
}
__device__ __forceinline__ float tanh_fast(float x) {
    float ax = fabsf(x);
    float e = __expf(-2.f * ax);
    float r = (1.f - e) / (1.f + e);
    return copysignf(r, x);
}
// butterfly add via DPP (VALU pipe, not LDS): v += perm(v). ctrl must be
// a compile-time constant -> template parameter.
template <int CTRL>
__device__ __forceinline__ float dpp_add(float v) {
    int x = __builtin_amdgcn_update_dpp(0, __builtin_bit_cast(int, v),
                                        CTRL, 0xf, 0xf, true);
    return v + __builtin_bit_cast(float, x);
}

// ---------------- Phase 1: xrow[t][gate*512+j][b] = dot(x[t,b,:], Wx[g][j,:]) ----------------
// (unchanged from R0 — known good; optimize later)
__global__ __launch_bounds__(256) void xproj_kernel(
    const float* __restrict__ x, const float* __restrict__ Wxi,
    const float* __restrict__ Wxc, const float* __restrict__ Wxo,
    float* __restrict__ xrow)
{
    extern __shared__ float lds[];
    float* xT = lds;                              // [256][65]
    const int tid = threadIdx.x, lane = tid & 63, wv = tid >> 6;
    float* wl = lds + 256 * 65 + wv * (8 * 256);  // per-wave [8 rows][256 k]
    const int t = blockIdx.x;

    for (int kh = 0; kh < 2; ++kh) {
        __syncthreads();
        for (int b = wv; b < 64; b += 4) {
            const float* xp = x + ((size_t)t * 64 + b) * 512 + kh * 256;
            #pragma unroll
            for (int q = 0; q < 4; ++q) {
                int k = lane + q * 64;
                xT[k * 65 + b] = xp[k];
            }
        }
        __syncthreads();

        for (int m = 0; m < 48; ++m) {
            const int Bk = wv + 4 * m;
            const int R0 = Bk * 8;
            #pragma unroll
            for (int r = 0; r < 8; ++r) {
                const int R = R0 + r, g = R >> 9, j = R & 511;
                const float* wsrc = (g == 0) ? Wxi : ((g == 1) ? Wxc : Wxo);
                const float4 w4 = *(const float4*)(wsrc + (size_t)j * 512 + kh * 256 + lane * 4);
                *(float4*)(wl + r * 256 + lane * 4) = w4;
            }
            float acc[8] = {0.f, 0.f, 0.f, 0.f, 0.f, 0.f, 0.f, 0.f};
            #pragma unroll 2
            for (int c = 0; c < 64; ++c) {
                const float x0 = xT[(4 * c + 0) * 65 + lane];
                const float x1 = xT[(4 * c + 1) * 65 + lane];
                const float x2 = xT[(4 * c + 2) * 65 + lane];
                const float x3 = xT[(4 * c + 3) * 65 + lane];
                #pragma unroll
                for (int r = 0; r < 8; ++r) {
                    const float4 w4 = *(const float4*)(wl + r * 256 + c * 4);
                    acc[r] += x0 * w4.x + x1 * w4.y + x2 * w4.z + x3 * w4.w;
                }
            }
            #pragma unroll
            for (int r = 0; r < 8; ++r) {
                const size_t o = ((size_t)t * NROW + R0 + r) * 64 + lane;
                if (kh) xrow[o] += acc[r];
                else    xrow[o]  = acc[r];
            }
        }
    }
}

// ---------------- Phase 2: batch-partitioned persistent scan ----------------
// 256 wgs x 384 thr. Group gid = blockIdx%8 owns batches [gid*8, gid*8+8) —
// groups are fully independent (recurrence is per-batch). Member m = blockIdx/8
// owns j-slice [m*16, m*16+16) x 3 gates = 48 rows, weights LDS-resident.
// Per step: group-local 32-arrival barrier; h exchange = 16 KB/wg via L3.
// GEMM: thread = (rg 0..11, ks 0..31); 4 rows x 8 batches in registers,
// k interleaved (k = ks + 32*i); DPP ror/bcast reduce over the 32-way k-split.
#define WPAD 52                        // w LDS row stride (16B-aligned, odd/16)
#define HPAD 12                        // h LDS row stride
#define W_FLOATS (512 * WPAD)          // 26624
#define H_FLOATS (512 * HPAD)          // 6144
__global__ __launch_bounds__(384) void scan_kernel(
    const float* __restrict__ xrow,
    const float* __restrict__ Whi, const float* __restrict__ Whc, const float* __restrict__ Who,
    const float* __restrict__ bi, const float* __restrict__ bc, const float* __restrict__ bo,
    float* __restrict__ hbuf, unsigned* __restrict__ bar, float* __restrict__ out)
{
    extern __shared__ float lds[];
    float* wlds = lds;                         // [512 k][52] rows rho = g*16+jloc
    float* hlds = lds + W_FLOATS;              // [512 k][12] b in 0..7
    float* gbuf = lds + W_FLOATS + H_FLOATS;   // [48 rho][8 b]
    float* biasL = gbuf + 384;                 // [48]

    const int tid = threadIdx.x, lane = tid & 63;
    const int gid = blockIdx.x & 7;            // batch group (XCD-aligned heuristic)
    const int m   = blockIdx.x >> 3;           // j-slice member 0..31
    const int rg  = tid >> 5, ks = tid & 31;   // GEMM coords (rg<12)

    // ---- one-time: stage 48 weight rows + biases ----
    for (int idx = tid; idx < 48 * 512; idx += 384) {
        const int rho = idx >> 9, k = idx & 511;
        const int g = rho >> 4, jloc = rho & 15;
        const float* wsrc = (g == 0) ? Whi : ((g == 1) ? Whc : Who);
        wlds[k * WPAD + rho] = wsrc[(size_t)(m * 16 + jloc) * 512 + k];
    }
    if (tid < 48) {
        const int g = tid >> 4, jloc = tid & 15;
        const float* bb = (g == 0) ? bi : ((g == 1) ? bc : bo);
        biasL[tid] = bb[m * 16 + jloc];
    }

    // epilogue identity: lane = jloc*8 + b (tid < 128)
    const int ejl = tid >> 3, eb = tid & 7;
    const int jg  = m * 16 + ejl;              // global j (epilogue threads)
    const int bg  = gid * 8 + eb;              // global batch
    float creg = 0.f;
    __syncthreads();

    unsigned* gctr = bar + gid * 32;           // group counter (128B apart)

    for (int t = 0; t < SEQ; ++t) {
        // ---- prefetch this step's xrow terms (independent of h) ----
        float xr0 = 0.f, xr1 = 0.f, xr2 = 0.f;
        if (tid < 128) {
            const size_t base = ((size_t)t * NROW + jg) * 64 + bg;
            xr0 = xrow[base];
            xr1 = xrow[base + (size_t)512 * 64];
            xr2 = xrow[base + (size_t)1024 * 64];
        }

        // ---- group barrier: wait for step-t h to be published ----
        if (tid == 0 && t > 0) {
            const unsigned tgt = (unsigned)(32 * t);
            while (__hip_atomic_load(gctr, __ATOMIC_RELAXED, __HIP_MEMORY_SCOPE_AGENT) < tgt)
                __builtin_amdgcn_s_sleep(1);
        }
        __syncthreads();

        // ---- stage h_t (16 KB: only our 8 batches), agent loads bypass L2 ----
        {
            const float* hsrc = hbuf + (size_t)(t & 1) * (BATCH * HID) + (size_t)gid * 8 * 512;
            for (int i = tid; i < 4096; i += 384) {
                const int b = i >> 9, k = i & 511;
                hlds[k * HPAD + b] =
                    __hip_atomic_load(hsrc + b * 512 + k, __ATOMIC_RELAXED, __HIP_MEMORY_SCOPE_AGENT);
            }
        }
        __syncthreads();

        // ---- GEMM: acc[r][b] = sum_k w[k][rg*4+r] * h[k][b], k = ks+32i ----
        float acc[4][8];
        #pragma unroll
        for (int r = 0; r < 4; ++r)
            #pragma unroll
            for (int b = 0; b < 8; ++b) acc[r][b] = 0.f;

        if (rg < 12) {
            const float* wb = wlds + ks * WPAD + rg * 4;
            const float* hb = hlds + ks * HPAD;
            #pragma unroll
            for (int i = 0; i < 16; ++i) {
                float wv[4], hv[8];
                *(float4*)&wv[0] = *(const float4*)(wb + i * (32 * WPAD));
                *(float4*)&hv[0] = *(const float4*)(hb + i * (32 * HPAD));
                *(float4*)&hv[4] = *(const float4*)(hb + i * (32 * HPAD) + 4);
                #pragma unroll
                for (int r = 0; r < 4; ++r)
                    #pragma unroll
                    for (int b = 0; b < 8; ++b)
                        acc[r][b] += wv[r] * hv[b];
            }
            // ---- reduce over ks (32 lanes per half-wave) on the VALU pipe ----
            #pragma unroll
            for (int r = 0; r < 4; ++r)
                #pragma unroll
                for (int b = 0; b < 8; ++b) {
                    float v = acc[r][b];
                    v = dpp_add<0x121>(v);  // row_ror:1
                    v = dpp_add<0x122>(v);  // row_ror:2
                    v = dpp_add<0x124>(v);  // row_ror:4
                    v = dpp_add<0x128>(v);  // row_ror:8  -> every lane has row16 sum
                    v = dpp_add<0x142>(v);  // row_bcast15 -> lanes 16..31/48..63 have 32-sum
                    acc[r][b] = v;
                }
            // result lanes: lane 16 (even rg of this wave) and lane 48 (odd rg)
            if (lane == 16 || lane == 48) {
                #pragma unroll
                for (int r = 0; r < 4; ++r) {
                    float* gp = gbuf + (rg * 4 + r) * 8;
                    *(float4*)gp       = make_float4(acc[r][0], acc[r][1], acc[r][2], acc[r][3]);
                    *(float4*)(gp + 4) = make_float4(acc[r][4], acc[r][5], acc[r][6], acc[r][7]);
                }
            }
        }
        __syncthreads();

        // ---- elementwise update (tid < 128): thread = (jloc, b) ----
        if (tid < 128) {
            const float pi = xr0 + biasL[ejl]      + gbuf[(0 * 16 + ejl) * 8 + eb];
            const float pc = xr1 + biasL[16 + ejl] + gbuf[(1 * 16 + ejl) * 8 + eb];
            const float po = xr2 + biasL[32 + ejl] + gbuf[(2 * 16 + ejl) * 8 + eb];
            const float it = sigf(pi);
            const float ch = tanh_fast(pc);
            const float ot = sigf(po);
            creg = (1.f - it) * creg + it * ch;       // coupled forget gate
            const float hn = ot * tanh_fast(creg);
            __hip_atomic_store(hbuf + (size_t)((t + 1) & 1) * (BATCH * HID) + (size_t)bg * 512 + jg,
                               hn, __ATOMIC_RELAXED, __HIP_MEMORY_SCOPE_AGENT);
            out[((size_t)t * 64 + bg) * 512 + jg] = hn;
            if (t == SEQ - 1) {
                out[SBH + (size_t)bg * 512 + jg] = hn;             // h_T
                out[SBH + 32768 + (size_t)bg * 512 + jg] = creg;   // c_T
            }
        }
        __threadfence();      // release: drain h stores before arrival
        __syncthreads();

        if (tid == 0)
            __hip_atomic_fetch_add(gctr, 1u, __ATOMIC_ACQ_REL, __HIP_MEMORY_SCOPE_AGENT);
    }
}

extern "C" void kernel_launch(void* const* d_in, const int* in_sizes, int n_in,
                              void* d_out, int out_size, void* d_ws, size_t ws_size,
                              hipStream_t stream)
{
    const float* x   = (const float*)d_in[0];
    const float* Wxi = (const float*)d_in[1];
    const float* Whi = (const float*)d_in[2];
    const float* bi  = (const float*)d_in[3];
    const float* Wxc = (const float*)d_in[4];
    const float* Whc = (const float*)d_in[5];
    const float* bc  = (const float*)d_in[6];
    const float* Wxo = (const float*)d_in[7];
    const float* Who = (const float*)d_in[8];
    const float* bo  = (const float*)d_in[9];
    float* out = (float*)d_out;
    char* ws = (char*)d_ws;

    float*    xrow = (float*)ws;
    float*    hbuf = (float*)(ws + XROW_FLOATS * 4);
    unsigned* bar  = (unsigned*)(ws + XROW_FLOATS * 4 + (size_t)HBUF_FLOATS * 4);

    // zero h_0 double-buffer + per-group barrier counters (ws re-poisoned 0xAA)
    (void)hipMemsetAsync(hbuf, 0, (size_t)HBUF_FLOATS * 4 + 1024, stream);

    hipLaunchKernelGGL(xproj_kernel, dim3(512), dim3(256), 99328, stream,
                       x, Wxi, Wxc, Wxo, xrow);
    // LDS: w 26624 + h 6144 + gbuf 384 + bias 48 = 33200 floats = 132800 B
    hipLaunchKernelGGL(scan_kernel, dim3(256), dim3(384), 132800, stream,
                       xrow, Whi, Whc, Who, bi, bc, bo, hbuf, bar, out);
}

// Round 4
// 6962.861 us; speedup vs baseline: 3.2081x; 3.2081x over previous
//
#include <hip/hip_runtime.h>
#include <math.h>

#define SEQ   512
#define BATCH 64
#define HID   512
#define NROW  1536                     // 3 gates * HID rows
#define XROW_FLOATS ((size_t)SEQ * NROW * BATCH)   // 201.3 MB
#define HBUF_FLOATS (2 * BATCH * HID)              // double-buffered h, [parity][b][j]
#define SBH ((size_t)SEQ * BATCH * HID)

__device__ __forceinline__ float sigf(float x) {
    return 1.f / (1.f + __expf(-x));
}
__device__ __forceinline__ float tanh_fast(float x) {
    float ax = fabsf(x);
    float e = __expf(-2.f * ax);
    float r = (1.f - e) / (1.f + e);
    return copysignf(r, x);
}
// butterfly add via DPP (VALU pipe, not LDS); ctrl is a template constant.
template <int CTRL>
__device__ __forceinline__ float dpp_add(float v) {
    int x = __builtin_amdgcn_update_dpp(0, __builtin_bit_cast(int, v),
                                        CTRL, 0xf, 0xf, true);
    return v + __builtin_bit_cast(float, x);
}

// ---------------- Phase 1: xrow[t][gate*512+j][b] = dot(x[t,b,:], Wx[g][j,:]) ----------------
// (unchanged — known good; optimize after the scan stops dominating)
__global__ __launch_bounds__(256) void xproj_kernel(
    const float* __restrict__ x, const float* __restrict__ Wxi,
    const float* __restrict__ Wxc, const float* __restrict__ Wxo,
    float* __restrict__ xrow)
{
    extern __shared__ float lds[];
    float* xT = lds;                              // [256][65]
    const int tid = threadIdx.x, lane = tid & 63, wv = tid >> 6;
    float* wl = lds + 256 * 65 + wv * (8 * 256);  // per-wave [8 rows][256 k]
    const int t = blockIdx.x;

    for (int kh = 0; kh < 2; ++kh) {
        __syncthreads();
        for (int b = wv; b < 64; b += 4) {
            const float* xp = x + ((size_t)t * 64 + b) * 512 + kh * 256;
            #pragma unroll
            for (int q = 0; q < 4; ++q) {
                int k = lane + q * 64;
                xT[k * 65 + b] = xp[k];
            }
        }
        __syncthreads();

        for (int m = 0; m < 48; ++m) {
            const int Bk = wv + 4 * m;
            const int R0 = Bk * 8;
            #pragma unroll
            for (int r = 0; r < 8; ++r) {
                const int R = R0 + r, g = R >> 9, j = R & 511;
                const float* wsrc = (g == 0) ? Wxi : ((g == 1) ? Wxc : Wxo);
                const float4 w4 = *(const float4*)(wsrc + (size_t)j * 512 + kh * 256 + lane * 4);
                *(float4*)(wl + r * 256 + lane * 4) = w4;
            }
            float acc[8] = {0.f, 0.f, 0.f, 0.f, 0.f, 0.f, 0.f, 0.f};
            #pragma unroll 2
            for (int c = 0; c < 64; ++c) {
                const float x0 = xT[(4 * c + 0) * 65 + lane];
                const float x1 = xT[(4 * c + 1) * 65 + lane];
                const float x2 = xT[(4 * c + 2) * 65 + lane];
                const float x3 = xT[(4 * c + 3) * 65 + lane];
                #pragma unroll
                for (int r = 0; r < 8; ++r) {
                    const float4 w4 = *(const float4*)(wl + r * 256 + c * 4);
                    acc[r] += x0 * w4.x + x1 * w4.y + x2 * w4.z + x3 * w4.w;
                }
            }
            #pragma unroll
            for (int r = 0; r < 8; ++r) {
                const size_t o = ((size_t)t * NROW + R0 + r) * 64 + lane;
                if (kh) xrow[o] += acc[r];
                else    xrow[o]  = acc[r];
            }
        }
    }
}

// ---------------- Phase 2: batch-partitioned persistent scan ----------------
// 256 wgs x 384 thr; group gid = blockIdx%8 owns 8 batches, member m = blockIdx/8
// owns 16 j x 3 gates = 48 rows (weights LDS-resident). Per step:
//   publish: h stores (agent, L2-bypass) -> s_waitcnt(0) -> barrier ->
//            tid0 release-stores flags[gid][m] = t+1  (NO atomic RMW)
//   wait:    lanes 0..31 poll the group's 32 packed flags (one 128B coalesced
//            load per iteration) until all >= t  (NO master hop)
// Flag set after consume(h_t)+publish(h_{t+1}) => parity double-buffer is safe.
#define WPAD 52                        // w LDS row stride
#define HPAD 12                        // h LDS row stride
#define W_FLOATS (512 * WPAD)          // 26624
#define H_FLOATS (512 * HPAD)          // 6144
__global__ __launch_bounds__(384) void scan_kernel(
    const float* __restrict__ xrow,
    const float* __restrict__ Whi, const float* __restrict__ Whc, const float* __restrict__ Who,
    const float* __restrict__ bi, const float* __restrict__ bc, const float* __restrict__ bo,
    float* __restrict__ hbuf, unsigned* __restrict__ flags, float* __restrict__ out)
{
    extern __shared__ float lds[];
    float* wlds = lds;                         // [512 k][52] rows rho = g*16+jloc
    float* hlds = lds + W_FLOATS;              // [512 k][12] b in 0..7
    float* gbuf = lds + W_FLOATS + H_FLOATS;   // [48 rho][8 b]
    float* biasL = gbuf + 384;                 // [48]

    const int tid = threadIdx.x, lane = tid & 63;
    const int gid = blockIdx.x & 7;            // batch group
    const int m   = blockIdx.x >> 3;           // j-slice member 0..31
    const int rg  = tid >> 5, ks = tid & 31;   // GEMM coords (rg<12)

    // ---- one-time: stage 48 weight rows + biases ----
    for (int idx = tid; idx < 48 * 512; idx += 384) {
        const int rho = idx >> 9, k = idx & 511;
        const int g = rho >> 4, jloc = rho & 15;
        const float* wsrc = (g == 0) ? Whi : ((g == 1) ? Whc : Who);
        wlds[k * WPAD + rho] = wsrc[(size_t)(m * 16 + jloc) * 512 + k];
    }
    if (tid < 48) {
        const int g = tid >> 4, jloc = tid & 15;
        const float* bb = (g == 0) ? bi : ((g == 1) ? bc : bo);
        biasL[tid] = bb[m * 16 + jloc];
    }

    // epilogue identity: tid = jloc*8 + b (tid < 128)
    const int ejl = tid >> 3, eb = tid & 7;
    const int jg  = m * 16 + ejl;              // global j
    const int bg  = gid * 8 + eb;              // global batch
    float creg = 0.f;
    __syncthreads();

    unsigned* gflags = flags + gid * 64;       // 32 packed dwords (one 128B line)

    for (int t = 0; t < SEQ; ++t) {
        // ---- prefetch this step's xrow terms (independent of h) ----
        float xr0 = 0.f, xr1 = 0.f, xr2 = 0.f;
        if (tid < 128) {
            const size_t base = ((size_t)t * NROW + jg) * 64 + bg;
            xr0 = xrow[base];
            xr1 = xrow[base + (size_t)512 * 64];
            xr2 = xrow[base + (size_t)1024 * 64];
        }

        // ---- wait: all 32 members have published h_t (flags >= t) ----
        if (tid < 64) {
            const unsigned tgt = (unsigned)t;
            while (true) {
                unsigned v = tgt;
                if (lane < 32)
                    v = __hip_atomic_load(gflags + lane, __ATOMIC_RELAXED,
                                          __HIP_MEMORY_SCOPE_AGENT);
                if (__all((int)(v >= tgt))) break;
                __builtin_amdgcn_s_sleep(4);
            }
        }
        __syncthreads();

        // ---- stage h_t (16 KB: our 8 batches), agent loads bypass L1/L2 ----
        {
            const float* hsrc = hbuf + (size_t)(t & 1) * (BATCH * HID) + (size_t)gid * 8 * 512;
            for (int i = tid; i < 4096; i += 384) {
                const int b = i >> 9, k = i & 511;
                hlds[k * HPAD + b] =
                    __hip_atomic_load(hsrc + b * 512 + k, __ATOMIC_RELAXED, __HIP_MEMORY_SCOPE_AGENT);
            }
        }
        __syncthreads();

        // ---- GEMM: acc[r][b] = sum_k w[k][rg*4+r] * h[k][b], k = ks+32i ----
        float acc[4][8];
        #pragma unroll
        for (int r = 0; r < 4; ++r)
            #pragma unroll
            for (int b = 0; b < 8; ++b) acc[r][b] = 0.f;

        if (rg < 12) {
            const float* wb = wlds + ks * WPAD + rg * 4;
            const float* hb = hlds + ks * HPAD;
            #pragma unroll
            for (int i = 0; i < 16; ++i) {
                float wv[4], hv[8];
                *(float4*)&wv[0] = *(const float4*)(wb + i * (32 * WPAD));
                *(float4*)&hv[0] = *(const float4*)(hb + i * (32 * HPAD));
                *(float4*)&hv[4] = *(const float4*)(hb + i * (32 * HPAD) + 4);
                #pragma unroll
                for (int r = 0; r < 4; ++r)
                    #pragma unroll
                    for (int b = 0; b < 8; ++b)
                        acc[r][b] += wv[r] * hv[b];
            }
            // ---- reduce over ks on the VALU pipe ----
            #pragma unroll
            for (int r = 0; r < 4; ++r)
                #pragma unroll
                for (int b = 0; b < 8; ++b) {
                    float v = acc[r][b];
                    v = dpp_add<0x121>(v);  // row_ror:1
                    v = dpp_add<0x122>(v);  // row_ror:2
                    v = dpp_add<0x124>(v);  // row_ror:4
                    v = dpp_add<0x128>(v);  // row_ror:8
                    v = dpp_add<0x142>(v);  // row_bcast15 -> lanes 16..31/48..63
                    acc[r][b] = v;
                }
            if (lane == 16 || lane == 48) {
                #pragma unroll
                for (int r = 0; r < 4; ++r) {
                    float* gp = gbuf + (rg * 4 + r) * 8;
                    *(float4*)gp       = make_float4(acc[r][0], acc[r][1], acc[r][2], acc[r][3]);
                    *(float4*)(gp + 4) = make_float4(acc[r][4], acc[r][5], acc[r][6], acc[r][7]);
                }
            }
        }
        __syncthreads();

        // ---- elementwise update (tid < 128): thread = (jloc, b) ----
        if (tid < 128) {
            const float pi = xr0 + biasL[ejl]      + gbuf[(0 * 16 + ejl) * 8 + eb];
            const float pc = xr1 + biasL[16 + ejl] + gbuf[(1 * 16 + ejl) * 8 + eb];
            const float po = xr2 + biasL[32 + ejl] + gbuf[(2 * 16 + ejl) * 8 + eb];
            const float it = sigf(pi);
            const float ch = tanh_fast(pc);
            const float ot = sigf(po);
            creg = (1.f - it) * creg + it * ch;       // coupled forget gate
            const float hn = ot * tanh_fast(creg);
            __hip_atomic_store(hbuf + (size_t)((t + 1) & 1) * (BATCH * HID) + (size_t)bg * 512 + jg,
                               hn, __ATOMIC_RELAXED, __HIP_MEMORY_SCOPE_AGENT);
            out[((size_t)t * 64 + bg) * 512 + jg] = hn;
            if (t == SEQ - 1) {
                out[SBH + (size_t)bg * 512 + jg] = hn;             // h_T
                out[SBH + 32768 + (size_t)bg * 512 + jg] = creg;   // c_T
            }
        }
        // drain h stores (pure waitcnt — no fence cache ops), then publish flag
        __builtin_amdgcn_s_waitcnt(0);
        __syncthreads();
        if (tid == 0)
            __hip_atomic_store(gflags + m, (unsigned)(t + 1),
                               __ATOMIC_RELEASE, __HIP_MEMORY_SCOPE_AGENT);
    }
}

extern "C" void kernel_launch(void* const* d_in, const int* in_sizes, int n_in,
                              void* d_out, int out_size, void* d_ws, size_t ws_size,
                              hipStream_t stream)
{
    const float* x   = (const float*)d_in[0];
    const float* Wxi = (const float*)d_in[1];
    const float* Whi = (const float*)d_in[2];
    const float* bi  = (const float*)d_in[3];
    const float* Wxc = (const float*)d_in[4];
    const float* Whc = (const float*)d_in[5];
    const float* bc  = (const float*)d_in[6];
    const float* Wxo = (const float*)d_in[7];
    const float* Who = (const float*)d_in[8];
    const float* bo  = (const float*)d_in[9];
    float* out = (float*)d_out;
    char* ws = (char*)d_ws;

    float*    xrow  = (float*)ws;
    float*    hbuf  = (float*)(ws + XROW_FLOATS * 4);
    unsigned* flags = (unsigned*)(ws + XROW_FLOATS * 4 + (size_t)HBUF_FLOATS * 4);

    // zero h_0 double-buffer + flags (8 groups x 64 dwords) every call
    (void)hipMemsetAsync(hbuf, 0, (size_t)HBUF_FLOATS * 4 + 2048, stream);

    hipLaunchKernelGGL(xproj_kernel, dim3(512), dim3(256), 99328, stream,
                       x, Wxi, Wxc, Wxo, xrow);
    // LDS: w 26624 + h 6144 + gbuf 384 + bias 48 = 33200 floats = 132800 B
    hipLaunchKernelGGL(scan_kernel, dim3(256), dim3(384), 132800, stream,
                       xrow, Whi, Whc, Who, bi, bc, bo, hbuf, flags, out);
}